// Round 1
// baseline (189.225 us; speedup 1.0000x reference)
//
#include <hip/hip_runtime.h>
#include <math.h>

#define TLEN 8192
#define NTH 256

__device__ __forceinline__ int padi(int i) { return i + (i >> 5); }

__global__ __launch_bounds__(NTH) void hurst_kernel(const float* __restrict__ x,
                                                    float* __restrict__ out) {
    // padded row buffer: raw x, then overwritten with inclusive prefix sum
    __shared__ float Q[TLEN + (TLEN >> 5)];   // 8448 floats = 33792 B
    __shared__ float wbuf[8];                 // wave partials: [0..3]=sum, [4..7]=sumsq
    __shared__ float SSp[257];                // exclusive prefix of segment sumsq (+ total)
    __shared__ float meanb[32];
    __shared__ float Rbuf[32];
    __shared__ float wred[8];                 // [0..3]=wave max, [4..7]=wave min
    __shared__ float lrbuf[8];

    const int t = threadIdx.x;
    const int lane = t & 63;
    const int wave = t >> 6;
    const long long row = blockIdx.x;
    const float* xr = x + row * TLEN;

    // ---- Phase 0: coalesced float4 load into padded LDS ----
    #pragma unroll
    for (int j = 0; j < 8; ++j) {
        int p = j * 1024 + t * 4;
        float4 v = *reinterpret_cast<const float4*>(xr + p);
        Q[padi(p + 0)] = v.x;
        Q[padi(p + 1)] = v.y;
        Q[padi(p + 2)] = v.z;
        Q[padi(p + 3)] = v.w;
    }
    __syncthreads();

    // ---- Phase A: per-thread contiguous 32-elem segment sum / sumsq ----
    float seg[32];
    const int base = t * 33;                  // padi(t*32)
    float ssum = 0.f, ssq = 0.f;
    #pragma unroll
    for (int k = 0; k < 32; ++k) {
        float v = Q[base + k];
        seg[k] = v;
        ssum += v;
        ssq += v * v;
    }

    // ---- block scans (sum + sumsq) over the 256 segment partials ----
    float v1 = ssum, v2 = ssq;
    #pragma unroll
    for (int d = 1; d < 64; d <<= 1) {
        float u1 = __shfl_up(v1, d, 64);
        float u2 = __shfl_up(v2, d, 64);
        if (lane >= d) { v1 += u1; v2 += u2; }
    }
    if (lane == 63) { wbuf[wave] = v1; wbuf[4 + wave] = v2; }
    __syncthreads();
    float woff1 = 0.f, woff2 = 0.f;
    for (int w = 0; w < wave; ++w) { woff1 += wbuf[w]; woff2 += wbuf[4 + w]; }
    const float ex1 = woff1 + v1 - ssum;      // exclusive prefix of segment sums
    const float ex2 = woff2 + v2 - ssq;       // exclusive prefix of segment sumsq
    SSp[t] = ex2;
    if (t == NTH - 1) SSp[256] = ex2 + ssq;

    // ---- Phase B: write inclusive global prefix sum in place ----
    float run = ex1;
    #pragma unroll
    for (int k = 0; k < 32; ++k) {
        run += seg[k];
        Q[base + k] = run;
    }
    __syncthreads();

    // ---- Phase 2: per-scale R/S ----
    const int p0 = t * 32;
    #pragma unroll
    for (int si = 0; si < 5; ++si) {
        const int s = 256 << si;              // 256,512,1024,2048,4096
        const int nc = TLEN / s;              // 32,16,8,4,2
        const int group = s >> 5;             // threads per chunk: 8..128

        // per-chunk mean from prefix sums
        if (t < nc) {
            float q1 = Q[padi((t + 1) * s - 1)];
            float q0 = (t > 0) ? Q[padi(t * s - 1)] : 0.f;
            meanb[t] = (q1 - q0) / (float)s;
        }
        __syncthreads();

        const int c = t / group;              // chunk of this thread
        const float m = meanb[c];             // broadcast read
        float hmax = -INFINITY, hmin = INFINITY;
        #pragma unroll
        for (int k = 0; k < 32; ++k) {
            float h = Q[base + k] - (float)(p0 + k + 1) * m;
            hmax = fmaxf(hmax, h);
            hmin = fminf(hmin, h);
        }
        // butterfly reduce within the chunk's lane group (chunk-aligned)
        #pragma unroll
        for (int w = 1; w < 64; w <<= 1) {
            if (w >= group) break;
            hmax = fmaxf(hmax, __shfl_xor(hmax, w, 64));
            hmin = fminf(hmin, __shfl_xor(hmin, w, 64));
        }
        if (group >= 128) {                   // s=4096: chunk spans 2 waves
            if (lane == 0) { wred[wave] = hmax; wred[4 + wave] = hmin; }
            __syncthreads();
            if (t < nc) {
                float a = fmaxf(wred[2 * t], wred[2 * t + 1]);
                float b = fminf(wred[4 + 2 * t], wred[4 + 2 * t + 1]);
                Rbuf[t] = a - b;
            }
        } else {
            if ((t & (group - 1)) == 0) Rbuf[c] = hmax - hmin;
        }
        __syncthreads();

        // rs per chunk in parallel (threads 0..nc-1), then wave-0 reduce
        float rs = 0.f;
        if (t < nc) {
            float m2 = meanb[t];
            int sg = s >> 5;
            float ss = SSp[(t + 1) * sg] - SSp[t * sg];
            float var = (ss - (float)s * m2 * m2) / (float)(s - 1);
            float S = fmaxf(sqrtf(fmaxf(var, 0.f)), 1e-8f);
            rs = fmaxf(Rbuf[t] / S, 1e-8f);
        }
        if (wave == 0) {
            #pragma unroll
            for (int w = 16; w >= 1; w >>= 1)
                rs += __shfl_down(rs, w, 64);
            if (lane == 0)
                lrbuf[si] = logf(fmaxf(rs / (float)nc, 1e-8f));
        }
        __syncthreads();
    }

    if (t == 0) {
        // ln(s) centered = (k-2)*ln2 ; den = 10*ln2^2 ; ln2 cancels once
        float num = -2.f * lrbuf[0] - lrbuf[1] + lrbuf[3] + 2.f * lrbuf[4];
        float H = num * (1.0f / (10.0f * 0.69314718055994530942f));
        H = fminf(fmaxf(H, 0.05f), 0.95f);
        out[row] = H;
    }
}

extern "C" void kernel_launch(void* const* d_in, const int* in_sizes, int n_in,
                              void* d_out, int out_size, void* d_ws, size_t ws_size,
                              hipStream_t stream) {
    const float* x = (const float*)d_in[0];
    float* out = (float*)d_out;
    const int B = in_sizes[0] / TLEN;         // 4096
    hurst_kernel<<<dim3(B), dim3(NTH), 0, stream>>>(x, out);
}